// Round 8
// baseline (87.771 us; speedup 1.0000x reference)
//
#include <hip/hip_runtime.h>
#include <hip/hip_bf16.h>

#define BATCH 512
#define PIX   65536
#define NOUT  512
#define COUT  4
#define NCLS  10

#define TP_BLOCKS 2048            // 256 pixel-windows x 8 row-groups
#define H_BLOCKS  64              // hist blocks (1024 px each)
#define Z_BLOCKS  32              // zero-hT blocks
#define TSTR      66              // LDS transpose stride (ushorts): bank=lane%32

__device__ __forceinline__ unsigned short f2bf(float f) {
    __hip_bfloat16 h = __float2bfloat16(f);      // RNE
    return *reinterpret_cast<unsigned short*>(&h);
}

// ---------------------------------------------------------------------------
// 1: transpose (x f32 -> xT bf16 [p][n]) || private-slab hist || zero hT ||
//    weff + out-init. One dispatch, disjoint outputs, no pre-zeroed globals.
// ---------------------------------------------------------------------------
__global__ __launch_bounds__(256) void fused1_kernel(
    const float* __restrict__ x, const int* __restrict__ seg,
    const float* __restrict__ W_fgl, const float* __restrict__ b_fgl,
    const float* __restrict__ W_fc,  const float* __restrict__ b_fc,
    unsigned short* __restrict__ xT, int* __restrict__ slab,
    float* __restrict__ hT, float* __restrict__ Weff, float* __restrict__ out)
{
    __shared__ __align__(16) unsigned char smem[256 * TSTR * 2];  // 33 KB
    const int bid = blockIdx.x, t = threadIdx.x;

    if (bid < TP_BLOCKS) {
        // ---------- transpose 64 rows x 256 pixels ----------
        unsigned short (*T2)[TSTR] = (unsigned short (*)[TSTR])smem;
        const int pw = bid & 255, rg = bid >> 8;
        const int n0 = rg * 64;

        // phase 1: row-major dword loads (1KB/instr), LDS writes bank=t%32 (free)
        const float* __restrict__ xp = x + (size_t)n0 * PIX + pw * 256 + t;
#pragma unroll 16
        for (int i = 0; i < 64; ++i)
            T2[t][i] = f2bf(xp[(size_t)i * PIX]);
        __syncthreads();

        // phase 2: dword LDS reads (<=2-way), uint4 stores 8 lanes/128B line
        const int c    = t & 7;          // 16B chunk within pixel's 128B row
        const int psub = t >> 3;         // 0..31
#pragma unroll
        for (int pg = 0; pg < 8; ++pg) {
            const int p = pg * 32 + psub;
            const unsigned* src = (const unsigned*)&T2[p][0];
            const uint4 val = make_uint4(src[c * 4 + 0], src[c * 4 + 1],
                                         src[c * 4 + 2], src[c * 4 + 3]);
            *(uint4*)(xT + (size_t)(pw * 256 + p) * BATCH + n0 + c * 8) = val;
        }
    } else if (bid < TP_BLOCKS + H_BLOCKS) {
        // ---------- private-slab histogram: 1024 px ----------
        int* lcnt = (int*)smem;
        const int hb = bid - TP_BLOCKS;
        lcnt[t] = 0; lcnt[t + 256] = 0;
        __syncthreads();
#pragma unroll
        for (int i = 0; i < 4; ++i)
            atomicAdd(&lcnt[seg[hb * 1024 + i * 256 + t]], 1);
        __syncthreads();
        slab[hb * NOUT + t]       = lcnt[t];
        slab[hb * NOUT + t + 256] = lcnt[t + 256];
    } else if (bid < TP_BLOCKS + H_BLOCKS + Z_BLOCKS) {
        // ---------- zero hT (1 MiB) ----------
        const int zb = bid - TP_BLOCKS - H_BLOCKS;
        float4* dst = (float4*)hT + (size_t)zb * 2048;
        const float4 z = make_float4(0.f, 0.f, 0.f, 0.f);
#pragma unroll
        for (int i = 0; i < 8; ++i) dst[i * 256 + t] = z;
    } else {
        // ---------- weff + out init (cst) ----------
        float* red = (float*)smem;
        float* cs  = red + 4 * NCLS;
        float cpart[NCLS];
#pragma unroll
        for (int k = 0; k < NCLS; ++k) cpart[k] = 0.f;
#pragma unroll
        for (int jj = 0; jj < 2; ++jj) {
            const int j = jj * 256 + t;
            float wf[COUT], bf[COUT];
#pragma unroll
            for (int cc = 0; cc < COUT; ++cc) {
                wf[cc] = W_fgl[cc * NOUT + j];
                bf[cc] = b_fgl[cc * NOUT + j];
            }
#pragma unroll
            for (int k = 0; k < NCLS; ++k) {
                float ww = 0.f, cb = 0.f;
#pragma unroll
                for (int cc = 0; cc < COUT; ++cc) {
                    const float wfc = W_fc[(cc * NOUT + j) * NCLS + k];
                    ww += wf[cc] * wfc;
                    cb += bf[cc] * wfc;
                }
                Weff[j * NCLS + k] = ww;
                cpart[k] += cb;
            }
        }
#pragma unroll
        for (int k = 0; k < NCLS; ++k)
#pragma unroll
            for (int off = 32; off; off >>= 1)
                cpart[k] += __shfl_down(cpart[k], off);
        if ((t & 63) == 0) {
#pragma unroll
            for (int k = 0; k < NCLS; ++k) red[(t >> 6) * NCLS + k] = cpart[k];
        }
        __syncthreads();
        if (t < NCLS) {
            float s = b_fc[t];
#pragma unroll
            for (int w2 = 0; w2 < 4; ++w2) s += red[w2 * NCLS + t];
            cs[t] = s;
        }
        __syncthreads();
        for (int i = t; i < BATCH * NCLS; i += 256) out[i] = cs[i % NCLS];
    }
}

// ---------------------------------------------------------------------------
// 2: cursor[j] = exclusive prefix over bin totals (sum of 64 slabs)
// ---------------------------------------------------------------------------
__global__ __launch_bounds__(512) void prefix_kernel(
    const int* __restrict__ slab, int* __restrict__ cursor)
{
    __shared__ int sc[NOUT];
    const int t = threadIdx.x;
    int s = 0;
#pragma unroll
    for (int b = 0; b < H_BLOCKS; ++b) s += slab[b * NOUT + t];
    sc[t] = s;
    __syncthreads();
    for (int off = 1; off < NOUT; off <<= 1) {
        const int u = (t >= off) ? sc[t - off] : 0;
        __syncthreads();
        sc[t] += u;
        __syncthreads();
    }
    cursor[t] = sc[t] - s;
}

// ---------------------------------------------------------------------------
// 3: globally bin-sorted pixel list. key = (bin<<16)|p.
// ---------------------------------------------------------------------------
__global__ __launch_bounds__(256) void scatter_kernel(
    const int* __restrict__ seg, int* __restrict__ cursor,
    unsigned* __restrict__ key)
{
#pragma unroll
    for (int i = 0; i < 4; ++i) {
        const int p = blockIdx.x * 1024 + i * 256 + threadIdx.x;
        const int b = seg[p];
        const int r = atomicAdd(&cursor[b], 1);
        key[r] = ((unsigned)b << 16) | (unsigned)p;
    }
}

// ---------------------------------------------------------------------------
// 4: segment sum. Wave = 256 batch rows (4/lane as uint2) x 64 sorted ranks.
// Scalar keys (SGPR) -> 16 batched 512B-coalesced loads in flight ->
// uniform-branch register-run accumulation -> rare coalesced atomic flushes.
// ---------------------------------------------------------------------------
__device__ __forceinline__ float bf_lo(unsigned u) {
    return __uint_as_float(u << 16);
}
__device__ __forceinline__ float bf_hi(unsigned u) {
    return __uint_as_float(u & 0xFFFF0000u);
}

__global__ __launch_bounds__(256) void segsum_kernel(
    const unsigned short* __restrict__ xT, const unsigned* __restrict__ key,
    float* __restrict__ hT)
{
    const int t = threadIdx.x, w = t >> 6, lane = t & 63;
    const int wid = blockIdx.x * 4 + w;      // 0..2047
    const int sg  = wid & 1023;              // rank segment (64 ranks)
    const int rg  = wid >> 10;               // row group (256 rows)
    const int nb  = rg * 256 + lane * 4;     // 4 rows per lane

    const unsigned kv = key[sg * 64 + lane];

    int   prev = __builtin_amdgcn_readlane((int)kv, 0) >> 16;
    float a0 = 0.f, a1 = 0.f, a2 = 0.f, a3 = 0.f;

#pragma unroll
    for (int c = 0; c < 4; ++c) {
        int   kb[16];
        uint2 v[16];
#pragma unroll
        for (int i = 0; i < 16; ++i) {
            const int ki = __builtin_amdgcn_readlane((int)kv, c * 16 + i);
            kb[i] = ki >> 16;
            v[i]  = *(const uint2*)(xT + (size_t)(ki & 0xFFFF) * BATCH + nb);
        }
#pragma unroll
        for (int i = 0; i < 16; ++i) {
            if (kb[i] != prev) {             // wave-uniform branch
                float* hp = &hT[(size_t)prev * BATCH + nb];
                unsafeAtomicAdd(hp + 0, a0);
                unsafeAtomicAdd(hp + 1, a1);
                unsafeAtomicAdd(hp + 2, a2);
                unsafeAtomicAdd(hp + 3, a3);
                prev = kb[i];
                a0 = a1 = a2 = a3 = 0.f;
            }
            a0 += bf_lo(v[i].x);
            a1 += bf_hi(v[i].x);
            a2 += bf_lo(v[i].y);
            a3 += bf_hi(v[i].y);
        }
    }
    float* hp = &hT[(size_t)prev * BATCH + nb];
    unsafeAtomicAdd(hp + 0, a0);
    unsafeAtomicAdd(hp + 1, a1);
    unsafeAtomicAdd(hp + 2, a2);
    unsafeAtomicAdd(hp + 3, a3);
}

// ---------------------------------------------------------------------------
// 5: out[n,k] += sum_j hT[j][n] * Weff[j,k]   (out pre-init = cst)
// ---------------------------------------------------------------------------
__global__ __launch_bounds__(256) void out_kernel(
    const float* __restrict__ hT, const float* __restrict__ Weff,
    float* __restrict__ out)
{
    __shared__ float wl[64 * NCLS];
    const int t  = threadIdx.x;
    const int jc = blockIdx.x >> 1;
    for (int i = t; i < 64 * NCLS; i += 256) wl[i] = Weff[jc * 64 * NCLS + i];
    __syncthreads();

    const int n = (blockIdx.x & 1) * 256 + t;
    float acc[NCLS] = {};
#pragma unroll
    for (int jj = 0; jj < 64; ++jj) {
        const float hv = hT[(size_t)(jc * 64 + jj) * BATCH + n];
#pragma unroll
        for (int k = 0; k < NCLS; ++k) acc[k] += hv * wl[jj * NCLS + k];
    }
#pragma unroll
    for (int k = 0; k < NCLS; ++k)
        unsafeAtomicAdd(&out[n * NCLS + k], acc[k]);
}

// ---------------------------------------------------------------------------
extern "C" void kernel_launch(void* const* d_in, const int* in_sizes, int n_in,
                              void* d_out, int out_size, void* d_ws, size_t ws_size,
                              hipStream_t stream)
{
    const float* x     = (const float*)d_in[0];
    const float* W_fgl = (const float*)d_in[1];
    const float* b_fgl = (const float*)d_in[2];
    const float* W_fc  = (const float*)d_in[3];
    const float* b_fc  = (const float*)d_in[4];
    const int*   seg   = (const int*)d_in[5];
    float*       out   = (float*)d_out;

    // ws: hT 1MB | Weff 20KB | slab 128KB | cursor 2KB | key 256KB | xT 64MB
    char* ws = (char*)d_ws;
    float*          hT     = (float*)ws;                           // 1048576
    float*          Weff   = (float*)(ws + 1048576);               // 20480
    int*            slab   = (int*)(ws + 1069056);                 // 131072
    int*            cursor = (int*)(ws + 1200128);                 // 2048
    unsigned*       key    = (unsigned*)(ws + 1202176);            // 262144
    unsigned short* xT     = (unsigned short*)(ws + 1464320);      // 64MB

    fused1_kernel <<<dim3(TP_BLOCKS + H_BLOCKS + Z_BLOCKS + 1), 256, 0, stream>>>(
        x, seg, W_fgl, b_fgl, W_fc, b_fc, xT, slab, hT, Weff, out);

    prefix_kernel <<<dim3(1),   512, 0, stream>>>(slab, cursor);
    scatter_kernel<<<dim3(64),  256, 0, stream>>>(seg, cursor, key);
    segsum_kernel <<<dim3(512), 256, 0, stream>>>(xT, key, hT);
    out_kernel    <<<dim3(16),  256, 0, stream>>>(hT, Weff, out);
}

// Round 10
// 35.076 us; speedup vs baseline: 2.5023x; 2.5023x over previous
//
#include <hip/hip_runtime.h>

#define BATCH 512
#define PIX   65536
#define NOUT  512
#define COUT  4
#define NCLS  10

#define KC    2048                // K-chunk (pixels) staged in LDS
#define NKC   (PIX / KC)          // 32
#define NRG   (BATCH / 8)         // 64 row-groups (8 rows per block)
#define AWROW 4112                // LDS row stride bytes: 2048*2 + 16 pad

// must match __builtin_amdgcn_cvt_pkrtz's return type exactly
typedef __fp16 half2_t __attribute__((ext_vector_type(2)));

#if __has_builtin(__builtin_amdgcn_fdot2)
__device__ __forceinline__ float fdot2f(half2_t a, half2_t b, float c) {
    return __builtin_amdgcn_fdot2(a, b, c, false);
}
#else
__device__ __forceinline__ float fdot2f(half2_t a, half2_t b, float c) {
    return c + (float)a[0] * (float)b[0] + (float)a[1] * (float)b[1];
}
#endif

// ---------------------------------------------------------------------------
// 0: Weff_h[j] (10 x f16, packed as 5 uints) = sum_c W_fgl[c,j]*W_fc[c*NOUT+j,:]
//    cst[k] = sum_{c,j} b_fgl[c,j]*W_fc[(c*NOUT+j),k] + b_fc[k];  out <- cst
// ---------------------------------------------------------------------------
__global__ __launch_bounds__(512) void weff_kernel(
    const float* __restrict__ W_fgl, const float* __restrict__ b_fgl,
    const float* __restrict__ W_fc,  const float* __restrict__ b_fc,
    unsigned* __restrict__ Weff_h, float* __restrict__ out)
{
    const int j = threadIdx.x;          // 0..511

    float wf[COUT], bf[COUT];
#pragma unroll
    for (int c = 0; c < COUT; ++c) {
        wf[c] = W_fgl[c * NOUT + j];
        bf[c] = b_fgl[c * NOUT + j];
    }

    float wv[NCLS], cpart[NCLS];
#pragma unroll
    for (int k = 0; k < NCLS; ++k) {
        float w = 0.f, cb = 0.f;
#pragma unroll
        for (int c = 0; c < COUT; ++c) {
            const float wfc = W_fc[(c * NOUT + j) * NCLS + k];
            w  += wf[c] * wfc;
            cb += bf[c] * wfc;
        }
        wv[k]    = w;
        cpart[k] = cb;
    }

#pragma unroll
    for (int k5 = 0; k5 < 5; ++k5) {
        const half2_t h = __builtin_amdgcn_cvt_pkrtz(wv[2 * k5], wv[2 * k5 + 1]);
        Weff_h[j * 5 + k5] = __builtin_bit_cast(unsigned, h);
    }

#pragma unroll
    for (int k = 0; k < NCLS; ++k)
#pragma unroll
        for (int off = 32; off; off >>= 1)
            cpart[k] += __shfl_down(cpart[k], off);

    __shared__ float red[8 * NCLS];
    __shared__ float cs[NCLS];
    if ((j & 63) == 0) {
#pragma unroll
        for (int k = 0; k < NCLS; ++k) red[(j >> 6) * NCLS + k] = cpart[k];
    }
    __syncthreads();
    if (j < NCLS) {
        float s = b_fc[j];
#pragma unroll
        for (int w = 0; w < 8; ++w) s += red[w * NCLS + j];
        cs[j] = s;
    }
    __syncthreads();
    for (int i = j; i < BATCH * NCLS; i += 512) out[i] = cs[i % NCLS];
}

// ---------------------------------------------------------------------------
// 1: AwT[k][p] (f16) = Weff_h[seg[p]][k].  Weff_h is 10KB -> L1-resident.
//    Stores: per k, lanes write consecutive p -> coalesced.
// ---------------------------------------------------------------------------
__global__ __launch_bounds__(256) void awbuild_kernel(
    const int* __restrict__ seg, const unsigned* __restrict__ Weff_h,
    unsigned short* __restrict__ AwT)
{
    const int p = blockIdx.x * 256 + threadIdx.x;
    const int j = seg[p];
    const unsigned* wrow = Weff_h + j * 5;
#pragma unroll
    for (int k5 = 0; k5 < 5; ++k5) {
        const unsigned u = wrow[k5];
        AwT[(size_t)(2 * k5)     * PIX + p] = (unsigned short)(u & 0xffffu);
        AwT[(size_t)(2 * k5 + 1) * PIX + p] = (unsigned short)(u >> 16);
    }
}

// ---------------------------------------------------------------------------
// 2: out[n,k] += sum_p x[n,p] * AwT[k][p]   (the whole network as one GEMM)
// Block = 8 rows x 2048-px chunk; AwT chunk in 40KB LDS (3 blocks/CU);
// wave = 2 rows over full chunk. Inner: float4 x (coalesced 1KB/instr),
// ds_read_b64 Aw (conflict-free), cvt_pkrtz + v_dot2_f32_f16.
// LDS tree-reduce; 80 atomics/block into cst-initialized out.
// ---------------------------------------------------------------------------
__global__ __launch_bounds__(256) void gemm_kernel(
    const float* __restrict__ x, const unsigned short* __restrict__ AwT,
    float* __restrict__ out)
{
    __shared__ __align__(16) char smem[10 * AWROW];   // 41120 B
    const int t    = threadIdx.x;
    const int rowg = blockIdx.x & (NRG - 1);
    const int kc   = blockIdx.x >> 6;
    const int pc   = kc * KC;

    // ---- stage AwT chunk: [10][2048] f16, conflict-free b128 writes ----
#pragma unroll
    for (int k = 0; k < NCLS; ++k) {
        const uint4 v = *(const uint4*)(AwT + (size_t)k * PIX + pc + t * 8);
        *(uint4*)(smem + k * AWROW + t * 16) = v;
    }
    __syncthreads();

    const int w = t >> 6, lane = t & 63;
    const int r0 = rowg * 8 + w * 2;
    const float4* __restrict__ xa = (const float4*)(x + (size_t)r0 * PIX + pc);
    const float4* __restrict__ xb = (const float4*)(x + (size_t)(r0 + 1) * PIX + pc);

    float acc0[NCLS] = {}, acc1[NCLS] = {};
#pragma unroll 2
    for (int i = 0; i < KC / 4 / 64; ++i) {          // 8 iterations
        const int px4 = i * 64 + lane;
        const float4 va = xa[px4];
        const float4 vb = xb[px4];
        uint2 awv[NCLS];
#pragma unroll
        for (int k = 0; k < NCLS; ++k)
            awv[k] = *(const uint2*)(smem + k * AWROW + px4 * 8);
        const half2_t a0 = __builtin_amdgcn_cvt_pkrtz(va.x, va.y);
        const half2_t a1 = __builtin_amdgcn_cvt_pkrtz(va.z, va.w);
        const half2_t b0 = __builtin_amdgcn_cvt_pkrtz(vb.x, vb.y);
        const half2_t b1 = __builtin_amdgcn_cvt_pkrtz(vb.z, vb.w);
#pragma unroll
        for (int k = 0; k < NCLS; ++k) {
            const half2_t wlo = __builtin_bit_cast(half2_t, awv[k].x);
            const half2_t whi = __builtin_bit_cast(half2_t, awv[k].y);
            acc0[k] = fdot2f(a1, whi, fdot2f(a0, wlo, acc0[k]));
            acc1[k] = fdot2f(b1, whi, fdot2f(b0, wlo, acc1[k]));
        }
    }
    __syncthreads();   // all awld reads done -> safe to overlay partials

    // ---- partials: part[j][264], j = r*10+k; column = one wave's 64 lanes ----
    float* part = (float*)smem;
#pragma unroll
    for (int k = 0; k < NCLS; ++k) {
        part[k * 264 + t]          = acc0[k];
        part[(10 + k) * 264 + t]   = acc1[k];
    }
    __syncthreads();

    if (t < 80) {
        const int w2 = t / 20, j = t % 20;
        const float4* src = (const float4*)(part + j * 264 + w2 * 64);
        float4 s4 = src[0];
#pragma unroll
        for (int q = 1; q < 16; ++q) {
            const float4 v = src[q];
            s4.x += v.x; s4.y += v.y; s4.z += v.z; s4.w += v.w;
        }
        const float s = (s4.x + s4.y) + (s4.z + s4.w);
        const int r = j / 10, k = j % 10;
        unsafeAtomicAdd(&out[(rowg * 8 + w2 * 2 + r) * NCLS + k], s);
    }
}

// ---------------------------------------------------------------------------
extern "C" void kernel_launch(void* const* d_in, const int* in_sizes, int n_in,
                              void* d_out, int out_size, void* d_ws, size_t ws_size,
                              hipStream_t stream)
{
    const float* x     = (const float*)d_in[0];
    const float* W_fgl = (const float*)d_in[1];
    const float* b_fgl = (const float*)d_in[2];
    const float* W_fc  = (const float*)d_in[3];
    const float* b_fc  = (const float*)d_in[4];
    const int*   seg   = (const int*)d_in[5];
    float*       out   = (float*)d_out;

    // ws: Weff_h [512][5] uint (10KB) | pad | AwT [10][65536] f16 (1.28MB)
    char*           ws     = (char*)d_ws;
    unsigned*       Weff_h = (unsigned*)ws;
    unsigned short* AwT    = (unsigned short*)(ws + 16384);

    weff_kernel   <<<dim3(1),          512, 0, stream>>>(W_fgl, b_fgl, W_fc, b_fc,
                                                         Weff_h, out);
    awbuild_kernel<<<dim3(PIX / 256),  256, 0, stream>>>(seg, Weff_h, AwT);
    gemm_kernel   <<<dim3(NRG * NKC),  256, 0, stream>>>(x, AwT, out);
}